// Round 2
// baseline (1508.787 us; speedup 1.0000x reference)
//
#include <hip/hip_runtime.h>

#define BATCH 32
#define NUM_CLASS 20
#define NTOT 16128      // 768 + 3072 + 12288
#define N0 768
#define N1 3072
#define MAX_BOXES 150
#define SORT_N 8192
#define CAND_CAP 7600
#define TOPK_N 4096     // >= NUM_CLASS*MAX_BOXES = 3000
#define SCORE_THRESH 0.3f
#define IOU_THRESH 0.1f

typedef unsigned long long u64;

// exp via double, rounded once to f32 (correctly-rounded center; halves worst-case
// distance to numpy's f32 exp). Remaining sigmoid arithmetic stays stepwise-f32
// to mirror a numpy 1/(1+exp(-x)) float32 evaluation.
__device__ __forceinline__ float exp_f32cr(float x) { return (float)exp((double)x); }
__device__ __forceinline__ float sigm(float x) { return 1.0f / (1.0f + exp_f32cr(-x)); }

// ---------------------------------------------------------------------------
// Kernel 1: decode all 3 feature maps -> corner boxes (B,N,4) + scores (B,C,N)
// scores stored class-major per image so NMS reads are coalesced.
// ---------------------------------------------------------------------------
__global__ __launch_bounds__(256) void decode_kernel(
    const float* __restrict__ fm0, const float* __restrict__ fm1,
    const float* __restrict__ fm2, const float* __restrict__ anchors,
    float* __restrict__ boxes, float* __restrict__ scores)
{
    int t = blockIdx.x * 256 + threadIdx.x;
    if (t >= BATCH * NTOT) return;
    int b = t / NTOT, n = t % NTOT;
    const float* fm; int g, arow, local;
    if (n < N0)           { fm = fm0; g = 16; arow = 6; local = n; }
    else if (n < N0 + N1) { fm = fm1; g = 32; arow = 3; local = n - N0; }
    else                  { fm = fm2; g = 64; arow = 0; local = n - (N0 + N1); }
    int cell = local / 3, a = local % 3;
    int gy = cell / g, gx = cell % g;
    const float* p = fm + ((size_t)((b * g + gy) * g + gx) * 75 + (size_t)a * 25);
    float s = 512.0f / (float)g;   // power of two: 32, 16, 8
    float cx = (sigm(p[0]) + (float)gx) * s;
    float cy = (sigm(p[1]) + (float)gy) * s;
    // ref: exp(t)*(anchor/s)*s == exp(t)*anchor exactly (pow2 scaling is exact)
    float w = exp_f32cr(p[2]) * anchors[(arow + a) * 2 + 0];
    float h = exp_f32cr(p[3]) * anchors[(arow + a) * 2 + 1];
    float conf = sigm(p[4]);
    float* bo = boxes + (size_t)t * 4;
    bo[0] = cx - w * 0.5f;
    bo[1] = cy - h * 0.5f;
    bo[2] = cx + w * 0.5f;
    bo[3] = cy + h * 0.5f;
    size_t sb = (size_t)b * NUM_CLASS * NTOT + (size_t)n;
    #pragma unroll
    for (int c = 0; c < NUM_CLASS; ++c)
        scores[sb + (size_t)c * NTOT] = conf * sigm(p[5 + c]);
}

// ---------------------------------------------------------------------------
// Kernel 2: per-(batch,class) greedy NMS.
// Equivalence: ref's 150-iter suppress loop == greedy "keep iff IoU<=thr vs
// all earlier keeps, in descending-score order (ties: lower index first)".
// LDS: single 64KB key array; tail slots (>= CAND_CAP) reused for kept boxes
// and scalars after sort (they only ever hold padding there).
// ---------------------------------------------------------------------------
__global__ __launch_bounds__(256) void nms_kernel(
    const float* __restrict__ boxes, const float* __restrict__ scores,
    int* __restrict__ kept_idx, float* __restrict__ kept_score)
{
    __shared__ u64 keys[SORT_N];
    const int tid = threadIdx.x;
    const int bc  = blockIdx.x;           // b*NUM_CLASS + c
    const int b   = bc / NUM_CLASS;

    unsigned int* scnt = (unsigned int*)&keys[SORT_N - 1]; // counter (pre-sort only)
    int*   sint = (int*)&keys[7880];       // [0]=firstIdx, [1]=nkept (post-sort only)
    float* kf   = (float*)&keys[7892];     // kept boxes: 4*150 floats (post-sort only)
    float* kx1 = kf, *ky1 = kf + MAX_BOXES, *kx2 = kf + 2*MAX_BOXES, *ky2 = kf + 3*MAX_BOXES;

    if (tid == 0) *scnt = 0u;
    __syncthreads();

    // 1. compact candidates (score > 0.3) into keys
    const float* sc = scores + (size_t)bc * NTOT;
    for (int n = tid; n < NTOT; n += 256) {
        float s = sc[n];
        if (s > SCORE_THRESH) {
            unsigned p = atomicAdd(scnt, 1u);
            if (p < CAND_CAP) {
                unsigned sbits = ~__float_as_uint(s); // ascending key = descending score
                keys[p] = ((u64)sbits << 32) | (unsigned)n;
            }
        }
    }
    __syncthreads();
    int cnt = (int)*scnt; if (cnt > CAND_CAP) cnt = CAND_CAP;
    __syncthreads();
    for (int i = cnt + tid; i < SORT_N; i += 256) keys[i] = ~0ull;

    // 2. bitonic sort (ascending)
    for (unsigned k = 2; k <= SORT_N; k <<= 1) {
        for (unsigned j = k >> 1; j > 0; j >>= 1) {
            __syncthreads();
            for (unsigned i = tid; i < SORT_N; i += 256) {
                unsigned ixj = i ^ j;
                if (ixj > i) {
                    u64 a = keys[i], bk = keys[ixj];
                    bool up = ((i & k) == 0);
                    if (up ? (a > bk) : (a < bk)) { keys[i] = bk; keys[ixj] = a; }
                }
            }
        }
    }
    __syncthreads();
    if (tid == 0) sint[1] = 0;
    __syncthreads();

    // 3. greedy scan, 256-candidate chunks
    const float* bbase = boxes + (size_t)b * NTOT * 4;
    for (int s0 = 0; s0 < cnt; s0 += 256) {
        int i = s0 + tid;
        int state = 1;                    // 0=unresolved survivor, 1=rejected, 2=kept
        float cx1=0, cy1=0, cx2=0, cy2=0, cs=0, carea=0; int cn = -1;
        int nk0 = sint[1];
        if (i < cnt) {
            u64 key = keys[i];
            cn = (int)(key & 0xffffffffull);
            cs = __uint_as_float(~(unsigned)(key >> 32));
            const float* bp = bbase + (size_t)cn * 4;
            cx1 = bp[0]; cy1 = bp[1]; cx2 = bp[2]; cy2 = bp[3];
            carea = (cx2 - cx1) * (cy2 - cy1);
            state = 0;
            for (int kk = 0; kk < nk0; ++kk) {     // pre-check vs existing keeps
                float ix1 = fmaxf(kx1[kk], cx1);
                float iy1 = fmaxf(ky1[kk], cy1);
                float ix2 = fminf(kx2[kk], cx2);
                float iy2 = fminf(ky2[kk], cy2);
                float inter = fmaxf(ix2 - ix1, 0.0f) * fmaxf(iy2 - iy1, 0.0f);
                float karea = (kx2[kk] - kx1[kk]) * (ky2[kk] - ky1[kk]);
                float iou = inter / (karea + carea - inter);
                if (iou > IOU_THRESH) { state = 1; break; }
            }
        }
        // resolve survivors in order; each iteration commits exactly one keep
        while (true) {
            __syncthreads();
            if (tid == 0) sint[0] = 256;
            __syncthreads();
            if (state == 0) atomicMin(&sint[0], tid);
            __syncthreads();
            int fi = sint[0];
            if (fi >= 256) break;                  // uniform
            int nk = sint[1];                      // uniform
            if (tid == fi) {
                kx1[nk] = cx1; ky1[nk] = cy1; kx2[nk] = cx2; ky2[nk] = cy2;
                kept_idx  [(size_t)bc * MAX_BOXES + nk] = cn;
                kept_score[(size_t)bc * MAX_BOXES + nk] = cs;
                sint[1] = nk + 1;
                state = 2;
            }
            __syncthreads();
            if (sint[1] >= MAX_BOXES) break;       // uniform
            if (state == 0) {                      // check vs the new keep
                float ix1 = fmaxf(kx1[nk], cx1);
                float iy1 = fmaxf(ky1[nk], cy1);
                float ix2 = fminf(kx2[nk], cx2);
                float iy2 = fminf(ky2[nk], cy2);
                float inter = fmaxf(ix2 - ix1, 0.0f) * fmaxf(iy2 - iy1, 0.0f);
                float karea = (kx2[nk] - kx1[nk]) * (ky2[nk] - ky1[nk]);
                float iou = inter / (karea + carea - inter);
                if (iou > IOU_THRESH) state = 1;
            }
        }
        __syncthreads();
        if (sint[1] >= MAX_BOXES) break;           // uniform
    }
    __syncthreads();
    int nkept = sint[1];
    for (int k = nkept + tid; k < MAX_BOXES; k += 256) {
        kept_idx  [(size_t)bc * MAX_BOXES + k] = -1;
        kept_score[(size_t)bc * MAX_BOXES + k] = -1.0f;
    }
}

// ---------------------------------------------------------------------------
// Kernel 3: per-image top-150 over 3000 kept entries (ties: lower flat pos).
// ---------------------------------------------------------------------------
__global__ __launch_bounds__(256) void topk_kernel(
    const float* __restrict__ boxes, const int* __restrict__ kept_idx,
    const float* __restrict__ kept_score, float* __restrict__ out)
{
    __shared__ u64 keys[TOPK_N];
    const int tid = threadIdx.x;
    const int b = blockIdx.x;
    const int FLAT = NUM_CLASS * MAX_BOXES;   // 3000

    for (int f = tid; f < TOPK_N; f += 256) {
        u64 key = ~0ull;
        if (f < FLAT) {
            int idx = kept_idx[(size_t)b * FLAT + f];
            float s = (idx >= 0) ? kept_score[(size_t)b * FLAT + f] : -1.0f;
            unsigned u = __float_as_uint(s);
            unsigned m = (u & 0x80000000u) ? ~u : (u | 0x80000000u); // order-preserving map
            key = ((u64)(~m) << 32) | (unsigned)f;  // ascending = score desc, pos asc
        }
        keys[f] = key;
    }
    for (unsigned k = 2; k <= TOPK_N; k <<= 1) {
        for (unsigned j = k >> 1; j > 0; j >>= 1) {
            __syncthreads();
            for (unsigned i = tid; i < TOPK_N; i += 256) {
                unsigned ixj = i ^ j;
                if (ixj > i) {
                    u64 a = keys[i], bk = keys[ixj];
                    bool up = ((i & k) == 0);
                    if (up ? (a > bk) : (a < bk)) { keys[i] = bk; keys[ixj] = a; }
                }
            }
        }
    }
    __syncthreads();
    if (tid < MAX_BOXES) {
        u64 key = keys[tid];
        int f = (int)(key & 0xffffffffull);
        float sc = -1.0f; int idx = -1;
        if (f < FLAT) {
            idx = kept_idx[(size_t)b * FLAT + f];
            if (idx >= 0) sc = kept_score[(size_t)b * FLAT + f];
        }
        bool ok = (idx >= 0) && (sc > 0.0f);
        float bx0 = -1.0f, bx1 = -1.0f, bx2 = -1.0f, bx3 = -1.0f;
        float lab = -1.0f;
        if (ok) {
            const float* bp = boxes + ((size_t)b * NTOT + idx) * 4;
            bx0 = bp[0]; bx1 = bp[1]; bx2 = bp[2]; bx3 = bp[3];
            lab = (float)(f / MAX_BOXES);
        } else {
            sc = -1.0f;
        }
        float* ob = out + ((size_t)b * MAX_BOXES + tid) * 4;
        ob[0] = bx0; ob[1] = bx1; ob[2] = bx2; ob[3] = bx3;
        out[(size_t)BATCH * MAX_BOXES * 4 + (size_t)b * MAX_BOXES + tid] = sc;
        out[(size_t)BATCH * MAX_BOXES * 5 + (size_t)b * MAX_BOXES + tid] = lab;
    }
}

extern "C" void kernel_launch(void* const* d_in, const int* in_sizes, int n_in,
                              void* d_out, int out_size, void* d_ws, size_t ws_size,
                              hipStream_t stream) {
    const float* fm0 = (const float*)d_in[0];
    const float* fm1 = (const float*)d_in[1];
    const float* fm2 = (const float*)d_in[2];
    const float* anchors = (const float*)d_in[3];
    float* out = (float*)d_out;

    // workspace carve
    float* boxes  = (float*)d_ws;                                  // B*N*4
    float* scores = boxes + (size_t)BATCH * NTOT * 4;              // B*C*N
    int*   kept_idx   = (int*)(scores + (size_t)BATCH * NUM_CLASS * NTOT);
    float* kept_score = (float*)(kept_idx + (size_t)BATCH * NUM_CLASS * MAX_BOXES);

    int total = BATCH * NTOT;
    decode_kernel<<<(total + 255) / 256, 256, 0, stream>>>(fm0, fm1, fm2, anchors, boxes, scores);
    nms_kernel<<<BATCH * NUM_CLASS, 256, 0, stream>>>(boxes, scores, kept_idx, kept_score);
    topk_kernel<<<BATCH, 256, 0, stream>>>(boxes, kept_idx, kept_score, out);
}

// Round 3
// 581.229 us; speedup vs baseline: 2.5959x; 2.5959x over previous
//
#include <hip/hip_runtime.h>

#define BATCH 32
#define NUM_CLASS 20
#define NTOT 16128      // 768 + 3072 + 12288
#define N0 768
#define N1 3072
#define MAX_BOXES 150
#define SORT_N 8192
#define CAND_CAP 7600
#define TOPK_N 4096     // >= NUM_CLASS*MAX_BOXES = 3000
#define SCORE_THRESH 0.3f
#define IOU_THRESH 0.1f
#define NMS_W 1024
#define NWAVES (NMS_W / 64)
#define TOPK_W 1024

typedef unsigned long long u64;

// exp via double, rounded once to f32 (correctly-rounded center, minimizes
// distance to numpy's f32 exp). Rest of sigmoid stays stepwise-f32.
__device__ __forceinline__ float exp_f32cr(float x) { return (float)exp((double)x); }
__device__ __forceinline__ float sigm(float x) { return 1.0f / (1.0f + exp_f32cr(-x)); }

// ---------------------------------------------------------------------------
// Kernel 1: decode -> corner boxes (B,N,4) + scores (B,C,N) class-major.
// ---------------------------------------------------------------------------
__global__ __launch_bounds__(256) void decode_kernel(
    const float* __restrict__ fm0, const float* __restrict__ fm1,
    const float* __restrict__ fm2, const float* __restrict__ anchors,
    float* __restrict__ boxes, float* __restrict__ scores)
{
    int t = blockIdx.x * 256 + threadIdx.x;
    if (t >= BATCH * NTOT) return;
    int b = t / NTOT, n = t % NTOT;
    const float* fm; int g, arow, local;
    if (n < N0)           { fm = fm0; g = 16; arow = 6; local = n; }
    else if (n < N0 + N1) { fm = fm1; g = 32; arow = 3; local = n - N0; }
    else                  { fm = fm2; g = 64; arow = 0; local = n - (N0 + N1); }
    int cell = local / 3, a = local % 3;
    int gy = cell / g, gx = cell % g;
    const float* p = fm + ((size_t)((b * g + gy) * g + gx) * 75 + (size_t)a * 25);
    float s = 512.0f / (float)g;   // power of two
    float cx = (sigm(p[0]) + (float)gx) * s;
    float cy = (sigm(p[1]) + (float)gy) * s;
    float w = exp_f32cr(p[2]) * anchors[(arow + a) * 2 + 0];
    float h = exp_f32cr(p[3]) * anchors[(arow + a) * 2 + 1];
    float conf = sigm(p[4]);
    float* bo = boxes + (size_t)t * 4;
    bo[0] = cx - w * 0.5f;
    bo[1] = cy - h * 0.5f;
    bo[2] = cx + w * 0.5f;
    bo[3] = cy + h * 0.5f;
    size_t sb = (size_t)b * NUM_CLASS * NTOT + (size_t)n;
    #pragma unroll
    for (int c = 0; c < NUM_CLASS; ++c)
        scores[sb + (size_t)c * NTOT] = conf * sigm(p[5 + c]);
}

// ---------------------------------------------------------------------------
// Kernel 2: per-(batch,class) greedy NMS (== ref's 150-iter suppress loop).
// 1024 threads; ballot-based resolve (no LDS atomics in hot loop);
// float4 kept boxes; group-of-4 pipelined pre-check.
// ---------------------------------------------------------------------------
__global__ __launch_bounds__(NMS_W, 8) void nms_kernel(
    const float* __restrict__ boxes, const float* __restrict__ scores,
    int* __restrict__ kept_idx, float* __restrict__ kept_score)
{
    __shared__ u64 keys[SORT_N];          // 64 KB
    __shared__ float4 kept4[MAX_BOXES];   // 2.4 KB
    __shared__ int wmin_s[NWAVES];
    __shared__ unsigned scnt_s;

    const int tid = threadIdx.x;
    const int wid = tid >> 6, wlane = tid & 63;
    const int bc = blockIdx.x;            // b*NUM_CLASS + c
    const int b  = bc / NUM_CLASS;

    if (tid == 0) scnt_s = 0u;
    __syncthreads();

    // 1. compact candidates (score > 0.3); ballot-aggregated append
    const float* sc = scores + (size_t)bc * NTOT;
    for (int n0 = 0; n0 < NTOT; n0 += NMS_W) {
        int n = n0 + tid;
        float s = (n < NTOT) ? sc[n] : -1.0f;
        bool pass = s > SCORE_THRESH;
        u64 m = __ballot(pass);
        unsigned base = 0;
        if (wlane == 0 && m) base = atomicAdd(&scnt_s, (unsigned)__popcll(m));
        base = __shfl(base, 0);
        if (pass) {
            unsigned pos = base + (unsigned)__popcll(m & ((1ull << wlane) - 1ull));
            if (pos < CAND_CAP) {
                unsigned sbits = ~__float_as_uint(s); // ascending = score desc, idx asc
                keys[pos] = ((u64)sbits << 32) | (unsigned)n;
            }
        }
    }
    __syncthreads();
    int cnt = (int)scnt_s; if (cnt > CAND_CAP) cnt = CAND_CAP;
    for (int i = cnt + tid; i < SORT_N; i += NMS_W) keys[i] = ~0ull;

    // 2. bitonic sort ascending (8 elems/thread, unrolled)
    for (unsigned k = 2; k <= SORT_N; k <<= 1) {
        for (unsigned j = k >> 1; j > 0; j >>= 1) {
            __syncthreads();
            #pragma unroll
            for (int r = 0; r < SORT_N / NMS_W; ++r) {
                unsigned i = (unsigned)(r * NMS_W + tid);
                unsigned ixj = i ^ j;
                if (ixj > i) {
                    u64 a = keys[i], bb = keys[ixj];
                    bool up = ((i & k) == 0);
                    if (up ? (a > bb) : (a < bb)) { keys[i] = bb; keys[ixj] = a; }
                }
            }
        }
    }
    __syncthreads();

    // 3. greedy scan in 1024-wide chunks
    const float* bbase = boxes + (size_t)b * NTOT * 4;
    const size_t obase = (size_t)bc * MAX_BOXES;
    int nk = 0;   // kept count, tracked uniformly in registers

    for (int s0 = 0; s0 < cnt && nk < MAX_BOXES; s0 += NMS_W) {
        int i = s0 + tid;
        int state = 1;                    // 0=survivor, 1=rejected/kept-done
        float4 c4 = make_float4(0.f, 0.f, 0.f, 0.f);
        float cs = 0.0f, carea = 0.0f; int cn = -1;
        if (i < cnt) {
            u64 key = keys[i];
            cn = (int)(key & 0xffffffffull);
            cs = __uint_as_float(~(unsigned)(key >> 32));
            c4 = *(const float4*)(bbase + (size_t)cn * 4);
            carea = (c4.z - c4.x) * (c4.w - c4.y);
            state = 0;
            // pre-check vs keeps known at chunk start, group-of-4 pipelined
            int kk = 0;
            for (; kk + 4 <= nk && state == 0; kk += 4) {
                bool rej = false;
                #pragma unroll
                for (int u = 0; u < 4; ++u) {
                    float4 kb = kept4[kk + u];
                    float ix1 = fmaxf(kb.x, c4.x), iy1 = fmaxf(kb.y, c4.y);
                    float ix2 = fminf(kb.z, c4.z), iy2 = fminf(kb.w, c4.w);
                    float inter = fmaxf(ix2 - ix1, 0.0f) * fmaxf(iy2 - iy1, 0.0f);
                    float ka = (kb.z - kb.x) * (kb.w - kb.y);
                    rej |= (inter / (ka + carea - inter)) > IOU_THRESH; // exact ref math
                }
                if (rej) state = 1;
            }
            for (; kk < nk && state == 0; ++kk) {
                float4 kb = kept4[kk];
                float ix1 = fmaxf(kb.x, c4.x), iy1 = fmaxf(kb.y, c4.y);
                float ix2 = fminf(kb.z, c4.z), iy2 = fminf(kb.w, c4.w);
                float inter = fmaxf(ix2 - ix1, 0.0f) * fmaxf(iy2 - iy1, 0.0f);
                float ka = (kb.z - kb.x) * (kb.w - kb.y);
                if ((inter / (ka + carea - inter)) > IOU_THRESH) state = 1;
            }
        }
        // resolve survivors in sorted order; one keep per iteration, 2 barriers
        while (true) {
            u64 m = __ballot(state == 0);
            if (wlane == 0) wmin_s[wid] = m ? (wid * 64 + (int)__builtin_ctzll(m)) : NMS_W;
            __syncthreads();
            int fi = wmin_s[0];
            #pragma unroll
            for (int w = 1; w < NWAVES; ++w) fi = min(fi, wmin_s[w]);
            if (fi >= NMS_W) break;        // uniform: no survivors left
            if (tid == fi) {
                kept4[nk] = c4;
                kept_idx  [obase + nk] = cn;
                kept_score[obase + nk] = cs;
                state = 2;
            }
            __syncthreads();
            if (state == 0) {              // re-check vs the new keep only
                float4 kb = kept4[nk];
                float ix1 = fmaxf(kb.x, c4.x), iy1 = fmaxf(kb.y, c4.y);
                float ix2 = fminf(kb.z, c4.z), iy2 = fminf(kb.w, c4.w);
                float inter = fmaxf(ix2 - ix1, 0.0f) * fmaxf(iy2 - iy1, 0.0f);
                float ka = (kb.z - kb.x) * (kb.w - kb.y);
                if ((inter / (ka + carea - inter)) > IOU_THRESH) state = 1;
            }
            ++nk;
            if (nk >= MAX_BOXES) break;    // uniform
        }
        __syncthreads();                   // kept4/wmin_s quiesce before next chunk
    }

    for (int kx = nk + tid; kx < MAX_BOXES; kx += NMS_W) {
        kept_idx  [obase + kx] = -1;
        kept_score[obase + kx] = -1.0f;
    }
}

// ---------------------------------------------------------------------------
// Kernel 3: per-image top-150 over 3000 kept entries (ties: lower flat pos).
// ---------------------------------------------------------------------------
__global__ __launch_bounds__(TOPK_W) void topk_kernel(
    const float* __restrict__ boxes, const int* __restrict__ kept_idx,
    const float* __restrict__ kept_score, float* __restrict__ out)
{
    __shared__ u64 keys[TOPK_N];
    const int tid = threadIdx.x;
    const int b = blockIdx.x;
    const int FLAT = NUM_CLASS * MAX_BOXES;   // 3000

    for (int f = tid; f < TOPK_N; f += TOPK_W) {
        u64 key = ~0ull;
        if (f < FLAT) {
            int idx = kept_idx[(size_t)b * FLAT + f];
            float s = (idx >= 0) ? kept_score[(size_t)b * FLAT + f] : -1.0f;
            unsigned u = __float_as_uint(s);
            unsigned mm = (u & 0x80000000u) ? ~u : (u | 0x80000000u);
            key = ((u64)(~mm) << 32) | (unsigned)f;  // ascending = score desc, pos asc
        }
        keys[f] = key;
    }
    for (unsigned k = 2; k <= TOPK_N; k <<= 1) {
        for (unsigned j = k >> 1; j > 0; j >>= 1) {
            __syncthreads();
            #pragma unroll
            for (int r = 0; r < TOPK_N / TOPK_W; ++r) {
                unsigned i = (unsigned)(r * TOPK_W + tid);
                unsigned ixj = i ^ j;
                if (ixj > i) {
                    u64 a = keys[i], bk = keys[ixj];
                    bool up = ((i & k) == 0);
                    if (up ? (a > bk) : (a < bk)) { keys[i] = bk; keys[ixj] = a; }
                }
            }
        }
    }
    __syncthreads();
    if (tid < MAX_BOXES) {
        u64 key = keys[tid];
        int f = (int)(key & 0xffffffffull);
        float sc = -1.0f; int idx = -1;
        if (f < FLAT) {
            idx = kept_idx[(size_t)b * FLAT + f];
            if (idx >= 0) sc = kept_score[(size_t)b * FLAT + f];
        }
        bool ok = (idx >= 0) && (sc > 0.0f);
        float bx0 = -1.0f, bx1 = -1.0f, bx2 = -1.0f, bx3 = -1.0f;
        float lab = -1.0f;
        if (ok) {
            const float* bp = boxes + ((size_t)b * NTOT + idx) * 4;
            bx0 = bp[0]; bx1 = bp[1]; bx2 = bp[2]; bx3 = bp[3];
            lab = (float)(f / MAX_BOXES);
        } else {
            sc = -1.0f;
        }
        float* ob = out + ((size_t)b * MAX_BOXES + tid) * 4;
        ob[0] = bx0; ob[1] = bx1; ob[2] = bx2; ob[3] = bx3;
        out[(size_t)BATCH * MAX_BOXES * 4 + (size_t)b * MAX_BOXES + tid] = sc;
        out[(size_t)BATCH * MAX_BOXES * 5 + (size_t)b * MAX_BOXES + tid] = lab;
    }
}

extern "C" void kernel_launch(void* const* d_in, const int* in_sizes, int n_in,
                              void* d_out, int out_size, void* d_ws, size_t ws_size,
                              hipStream_t stream) {
    const float* fm0 = (const float*)d_in[0];
    const float* fm1 = (const float*)d_in[1];
    const float* fm2 = (const float*)d_in[2];
    const float* anchors = (const float*)d_in[3];
    float* out = (float*)d_out;

    float* boxes  = (float*)d_ws;                                  // B*N*4
    float* scores = boxes + (size_t)BATCH * NTOT * 4;              // B*C*N
    int*   kept_idx   = (int*)(scores + (size_t)BATCH * NUM_CLASS * NTOT);
    float* kept_score = (float*)(kept_idx + (size_t)BATCH * NUM_CLASS * MAX_BOXES);

    int total = BATCH * NTOT;
    decode_kernel<<<(total + 255) / 256, 256, 0, stream>>>(fm0, fm1, fm2, anchors, boxes, scores);
    nms_kernel<<<BATCH * NUM_CLASS, NMS_W, 0, stream>>>(boxes, scores, kept_idx, kept_score);
    topk_kernel<<<BATCH, TOPK_W, 0, stream>>>(boxes, kept_idx, kept_score, out);
}

// Round 4
// 552.511 us; speedup vs baseline: 2.7308x; 1.0520x over previous
//
#include <hip/hip_runtime.h>

#define BATCH 32
#define NUM_CLASS 20
#define NTOT 16128      // 768 + 3072 + 12288
#define N0 768
#define N1 3072
#define MAX_BOXES 150
#define SORT_N 8192
#define CAND_CAP 7600
#define TOPK_N 4096     // >= NUM_CLASS*MAX_BOXES = 3000
#define SCORE_THRESH 0.3f
#define IOU_THRESH 0.1f
#define NMS_W 1024
#define SCAN_WPB 4      // waves (problems) per scan block
#define TOPK_W 1024

typedef unsigned long long u64;

// exp via double, rounded once to f32 (correctly-rounded center, minimizes
// distance to numpy's f32 exp). Rest of sigmoid stays stepwise-f32.
__device__ __forceinline__ float exp_f32cr(float x) { return (float)exp((double)x); }
__device__ __forceinline__ float sigm(float x) { return 1.0f / (1.0f + exp_f32cr(-x)); }

__device__ __forceinline__ bool iou_rej(float4 kb, float4 c4, float carea) {
    float ix1 = fmaxf(kb.x, c4.x), iy1 = fmaxf(kb.y, c4.y);
    float ix2 = fminf(kb.z, c4.z), iy2 = fminf(kb.w, c4.w);
    float inter = fmaxf(ix2 - ix1, 0.0f) * fmaxf(iy2 - iy1, 0.0f);
    float ka = (kb.z - kb.x) * (kb.w - kb.y);
    return (inter / (ka + carea - inter)) > IOU_THRESH;   // exact ref math
}

// ---------------------------------------------------------------------------
// Kernel 1: decode -> corner boxes (B,N,4) + scores (B,C,N) class-major.
// ---------------------------------------------------------------------------
__global__ __launch_bounds__(256) void decode_kernel(
    const float* __restrict__ fm0, const float* __restrict__ fm1,
    const float* __restrict__ fm2, const float* __restrict__ anchors,
    float* __restrict__ boxes, float* __restrict__ scores)
{
    int t = blockIdx.x * 256 + threadIdx.x;
    if (t >= BATCH * NTOT) return;
    int b = t / NTOT, n = t % NTOT;
    const float* fm; int g, arow, local;
    if (n < N0)           { fm = fm0; g = 16; arow = 6; local = n; }
    else if (n < N0 + N1) { fm = fm1; g = 32; arow = 3; local = n - N0; }
    else                  { fm = fm2; g = 64; arow = 0; local = n - (N0 + N1); }
    int cell = local / 3, a = local % 3;
    int gy = cell / g, gx = cell % g;
    const float* p = fm + ((size_t)((b * g + gy) * g + gx) * 75 + (size_t)a * 25);
    float s = 512.0f / (float)g;   // power of two
    float cx = (sigm(p[0]) + (float)gx) * s;
    float cy = (sigm(p[1]) + (float)gy) * s;
    float w = exp_f32cr(p[2]) * anchors[(arow + a) * 2 + 0];
    float h = exp_f32cr(p[3]) * anchors[(arow + a) * 2 + 1];
    float conf = sigm(p[4]);
    float* bo = boxes + (size_t)t * 4;
    bo[0] = cx - w * 0.5f;
    bo[1] = cy - h * 0.5f;
    bo[2] = cx + w * 0.5f;
    bo[3] = cy + h * 0.5f;
    size_t sb = (size_t)b * NUM_CLASS * NTOT + (size_t)n;
    #pragma unroll
    for (int c = 0; c < NUM_CLASS; ++c)
        scores[sb + (size_t)c * NTOT] = conf * sigm(p[5 + c]);
}

// ---------------------------------------------------------------------------
// Kernel 2a: per-(batch,class) compact + bitonic sort; sorted keys -> global.
// key = (~score_bits << 32) | idx : ascending == (score desc, idx asc),
// identical to jnp.argsort(-s) stable order.
// ---------------------------------------------------------------------------
__global__ __launch_bounds__(NMS_W, 8) void sort_kernel(
    const float* __restrict__ scores, u64* __restrict__ skeys,
    int* __restrict__ scnt_g)
{
    __shared__ u64 keys[SORT_N];          // 64 KB
    __shared__ unsigned scnt_s;

    const int tid = threadIdx.x;
    const int wlane = tid & 63;
    const int bc = blockIdx.x;            // b*NUM_CLASS + c

    if (tid == 0) scnt_s = 0u;
    __syncthreads();

    // 1. compact candidates (score > 0.3); ballot-aggregated append
    const float* sc = scores + (size_t)bc * NTOT;
    for (int n0 = 0; n0 < NTOT; n0 += NMS_W) {
        int n = n0 + tid;
        float s = (n < NTOT) ? sc[n] : -1.0f;
        bool pass = s > SCORE_THRESH;
        u64 m = __ballot(pass);
        unsigned base = 0;
        if (wlane == 0 && m) base = atomicAdd(&scnt_s, (unsigned)__popcll(m));
        base = __shfl(base, 0);
        if (pass) {
            unsigned pos = base + (unsigned)__popcll(m & ((1ull << wlane) - 1ull));
            if (pos < CAND_CAP) {
                unsigned sbits = ~__float_as_uint(s);
                keys[pos] = ((u64)sbits << 32) | (unsigned)n;
            }
        }
    }
    __syncthreads();
    int cnt = (int)scnt_s; if (cnt > CAND_CAP) cnt = CAND_CAP;
    for (int i = cnt + tid; i < SORT_N; i += NMS_W) keys[i] = ~0ull;

    // 2. bitonic sort ascending (8 elems/thread)
    for (unsigned k = 2; k <= SORT_N; k <<= 1) {
        for (unsigned j = k >> 1; j > 0; j >>= 1) {
            __syncthreads();
            #pragma unroll
            for (int r = 0; r < SORT_N / NMS_W; ++r) {
                unsigned i = (unsigned)(r * NMS_W + tid);
                unsigned ixj = i ^ j;
                if (ixj > i) {
                    u64 a = keys[i], bb = keys[ixj];
                    bool up = ((i & k) == 0);
                    if (up ? (a > bb) : (a < bb)) { keys[i] = bb; keys[ixj] = a; }
                }
            }
        }
    }
    __syncthreads();

    // 3. write sorted keys + count to global
    u64* ko = skeys + (size_t)bc * SORT_N;
    #pragma unroll
    for (int r = 0; r < SORT_N / NMS_W; ++r)
        ko[r * NMS_W + tid] = keys[r * NMS_W + tid];
    if (tid == 0) scnt_g[bc] = cnt;
}

// ---------------------------------------------------------------------------
// Kernel 2b: greedy scan, ONE WAVE per (b,c) problem — zero barriers.
// Greedy == ref's 150-iter suppress loop (keep iff IoU<=thr vs earlier keeps).
// ---------------------------------------------------------------------------
__global__ __launch_bounds__(64 * SCAN_WPB) void scan_kernel(
    const float* __restrict__ boxes, const u64* __restrict__ skeys,
    const int* __restrict__ scnt_g,
    int* __restrict__ kept_idx, float* __restrict__ kept_score)
{
    __shared__ float4 kept_s[SCAN_WPB][MAX_BOXES];
    const int wid = threadIdx.x >> 6, lane = threadIdx.x & 63;
    const int bc = blockIdx.x * SCAN_WPB + wid;
    const int b  = bc / NUM_CLASS;
    float4* kept = kept_s[wid];

    const u64* keys = skeys + (size_t)bc * SORT_N;
    int cnt = scnt_g[bc]; if (cnt > CAND_CAP) cnt = CAND_CAP;
    const float* bbase = boxes + (size_t)b * NTOT * 4;
    const size_t obase = (size_t)bc * MAX_BOXES;
    int nk = 0;

    for (int s0 = 0; s0 < cnt && nk < MAX_BOXES; s0 += 64) {
        int i = s0 + lane;
        int state = 1;                    // 0=survivor, 1=rejected, 2=kept
        float4 c4 = make_float4(0.f, 0.f, 0.f, 0.f);
        float cs = 0.0f, carea = 0.0f; int cn = -1;
        if (i < cnt) {
            u64 key = keys[i];
            cn = (int)(key & 0xffffffffull);
            cs = __uint_as_float(~(unsigned)(key >> 32));
            c4 = *(const float4*)(bbase + (size_t)cn * 4);
            carea = (c4.z - c4.x) * (c4.w - c4.y);
            state = 0;
            for (int kk = 0; kk < nk; ++kk) {      // pre-check vs existing keeps
                if (iou_rej(kept[kk], c4, carea)) { state = 1; break; }
            }
        }
        // wave-serial resolve: ballot + shfl, no barriers
        while (nk < MAX_BOXES) {
            u64 m = __ballot(state == 0);
            if (!m) break;
            int fi = (int)__builtin_ctzll(m);
            float4 kb;
            kb.x = __shfl(c4.x, fi); kb.y = __shfl(c4.y, fi);
            kb.z = __shfl(c4.z, fi); kb.w = __shfl(c4.w, fi);
            int   kn = __shfl(cn, fi);
            float ks = __shfl(cs, fi);
            if (lane == 0) {
                kept[nk] = kb;
                kept_idx  [obase + nk] = kn;
                kept_score[obase + nk] = ks;
            }
            if (lane == fi) state = 2;
            else if (state == 0 && iou_rej(kb, c4, carea)) state = 1;
            ++nk;
        }
    }
    for (int kx = nk + lane; kx < MAX_BOXES; kx += 64) {
        kept_idx  [obase + kx] = -1;
        kept_score[obase + kx] = -1.0f;
    }
}

// ---------------------------------------------------------------------------
// Kernel 3: per-image top-150 over 3000 kept entries (ties: lower flat pos).
// ---------------------------------------------------------------------------
__global__ __launch_bounds__(TOPK_W) void topk_kernel(
    const float* __restrict__ boxes, const int* __restrict__ kept_idx,
    const float* __restrict__ kept_score, float* __restrict__ out)
{
    __shared__ u64 keys[TOPK_N];
    const int tid = threadIdx.x;
    const int b = blockIdx.x;
    const int FLAT = NUM_CLASS * MAX_BOXES;   // 3000

    for (int f = tid; f < TOPK_N; f += TOPK_W) {
        u64 key = ~0ull;
        if (f < FLAT) {
            int idx = kept_idx[(size_t)b * FLAT + f];
            float s = (idx >= 0) ? kept_score[(size_t)b * FLAT + f] : -1.0f;
            unsigned u = __float_as_uint(s);
            unsigned mm = (u & 0x80000000u) ? ~u : (u | 0x80000000u);
            key = ((u64)(~mm) << 32) | (unsigned)f;  // ascending = score desc, pos asc
        }
        keys[f] = key;
    }
    for (unsigned k = 2; k <= TOPK_N; k <<= 1) {
        for (unsigned j = k >> 1; j > 0; j >>= 1) {
            __syncthreads();
            #pragma unroll
            for (int r = 0; r < TOPK_N / TOPK_W; ++r) {
                unsigned i = (unsigned)(r * TOPK_W + tid);
                unsigned ixj = i ^ j;
                if (ixj > i) {
                    u64 a = keys[i], bk = keys[ixj];
                    bool up = ((i & k) == 0);
                    if (up ? (a > bk) : (a < bk)) { keys[i] = bk; keys[ixj] = a; }
                }
            }
        }
    }
    __syncthreads();
    if (tid < MAX_BOXES) {
        u64 key = keys[tid];
        int f = (int)(key & 0xffffffffull);
        float sc = -1.0f; int idx = -1;
        if (f < FLAT) {
            idx = kept_idx[(size_t)b * FLAT + f];
            if (idx >= 0) sc = kept_score[(size_t)b * FLAT + f];
        }
        bool ok = (idx >= 0) && (sc > 0.0f);
        float bx0 = -1.0f, bx1 = -1.0f, bx2 = -1.0f, bx3 = -1.0f;
        float lab = -1.0f;
        if (ok) {
            const float* bp = boxes + ((size_t)b * NTOT + idx) * 4;
            bx0 = bp[0]; bx1 = bp[1]; bx2 = bp[2]; bx3 = bp[3];
            lab = (float)(f / MAX_BOXES);
        } else {
            sc = -1.0f;
        }
        float* ob = out + ((size_t)b * MAX_BOXES + tid) * 4;
        ob[0] = bx0; ob[1] = bx1; ob[2] = bx2; ob[3] = bx3;
        out[(size_t)BATCH * MAX_BOXES * 4 + (size_t)b * MAX_BOXES + tid] = sc;
        out[(size_t)BATCH * MAX_BOXES * 5 + (size_t)b * MAX_BOXES + tid] = lab;
    }
}

extern "C" void kernel_launch(void* const* d_in, const int* in_sizes, int n_in,
                              void* d_out, int out_size, void* d_ws, size_t ws_size,
                              hipStream_t stream) {
    const float* fm0 = (const float*)d_in[0];
    const float* fm1 = (const float*)d_in[1];
    const float* fm2 = (const float*)d_in[2];
    const float* anchors = (const float*)d_in[3];
    float* out = (float*)d_out;

    // workspace carve (all 16B-aligned)
    float* boxes  = (float*)d_ws;                                   // B*N*4        (8.25 MB)
    float* scores = boxes + (size_t)BATCH * NTOT * 4;               // B*C*N        (41.3 MB)
    u64*   skeys  = (u64*)(scores + (size_t)BATCH * NUM_CLASS * NTOT); // B*C*SORT_N (40 MB)
    int*   scnt   = (int*)(skeys + (size_t)BATCH * NUM_CLASS * SORT_N);
    int*   kept_idx   = scnt + BATCH * NUM_CLASS;
    float* kept_score = (float*)(kept_idx + (size_t)BATCH * NUM_CLASS * MAX_BOXES);

    int total = BATCH * NTOT;
    decode_kernel<<<(total + 255) / 256, 256, 0, stream>>>(fm0, fm1, fm2, anchors, boxes, scores);
    sort_kernel<<<BATCH * NUM_CLASS, NMS_W, 0, stream>>>(scores, skeys, scnt);
    scan_kernel<<<BATCH * NUM_CLASS / SCAN_WPB, 64 * SCAN_WPB, 0, stream>>>(
        boxes, skeys, scnt, kept_idx, kept_score);
    topk_kernel<<<BATCH, TOPK_W, 0, stream>>>(boxes, kept_idx, kept_score, out);
}

// Round 5
// 455.838 us; speedup vs baseline: 3.3099x; 1.2121x over previous
//
#include <hip/hip_runtime.h>

#define BATCH 32
#define NUM_CLASS 20
#define NTOT 16128      // 768 + 3072 + 12288
#define N0 768
#define N1 3072
#define MAX_BOXES 150
#define SORT_N 8192
#define CAND_CAP 7600
#define TOPK_N 4096     // >= NUM_CLASS*MAX_BOXES = 3000
#define SCORE_THRESH 0.3f
#define IOU_THRESH 0.1f
#define NMS_W 1024
#define TOPK_W 1024

typedef unsigned long long u64;

// exp via double, rounded once to f32 (correctly-rounded center, minimizes
// distance to numpy's f32 exp). Rest of sigmoid stays stepwise-f32.
__device__ __forceinline__ float exp_f32cr(float x) { return (float)exp((double)x); }
__device__ __forceinline__ float sigm(float x) { return 1.0f / (1.0f + exp_f32cr(-x)); }

__device__ __forceinline__ bool iou_rej(float4 kb, float4 c4, float carea) {
    float ix1 = fmaxf(kb.x, c4.x), iy1 = fmaxf(kb.y, c4.y);
    float ix2 = fminf(kb.z, c4.z), iy2 = fminf(kb.w, c4.w);
    float inter = fmaxf(ix2 - ix1, 0.0f) * fmaxf(iy2 - iy1, 0.0f);
    float ka = (kb.z - kb.x) * (kb.w - kb.y);
    return (inter / (ka + carea - inter)) > IOU_THRESH;   // exact ref math
}

// ---------------------------------------------------------------------------
// Register-blocked bitonic sort over THREADS*VPT u64 keys living in `lds`.
// Thread t owns contiguous elements [t*VPT, (t+1)*VPT).
//   j <  VPT        : in-register compare-exchange (no LDS, no barrier)
//   VPT <= j < 64*VPT: partner lane-dist j/VPT in [1,63] -> __shfl_xor
//   j >= 64*VPT     : cross-wave -> LDS exchange (2 barriers/stage)
// Only ~10 of 91 stages touch LDS (SORT_N=8192, VPT=8).
// ---------------------------------------------------------------------------
template<int VPT>
__device__ __forceinline__ void bitonic_reg_sort(u64* lds, int tid, int nthreads) {
    const int N = nthreads * VPT;
    u64 r[VPT];
    #pragma unroll
    for (int e = 0; e < VPT; ++e) r[e] = lds[tid * VPT + e];

    for (int k = 2; k <= N; k <<= 1) {
        int j = k >> 1;
        for (; j >= 64 * VPT; j >>= 1) {            // cross-wave: LDS
            __syncthreads();
            #pragma unroll
            for (int e = 0; e < VPT; ++e) lds[tid * VPT + e] = r[e];
            __syncthreads();
            #pragma unroll
            for (int e = 0; e < VPT; ++e) {
                int i = tid * VPT + e;
                u64 q = lds[i ^ j];
                bool takeMin = (((i & k) == 0) == ((i & j) == 0));
                bool less = r[e] < q;
                r[e] = (takeMin == less) ? r[e] : q;
            }
        }
        for (; j >= VPT; j >>= 1) {                 // in-wave: shfl_xor
            int ld = j / VPT;
            #pragma unroll
            for (int e = 0; e < VPT; ++e) {
                unsigned lo = (unsigned)r[e], hi = (unsigned)(r[e] >> 32);
                lo = (unsigned)__shfl_xor((int)lo, ld);
                hi = (unsigned)__shfl_xor((int)hi, ld);
                u64 q = ((u64)hi << 32) | lo;
                int i = tid * VPT + e;
                bool takeMin = (((i & k) == 0) == ((i & j) == 0));
                bool less = r[e] < q;
                r[e] = (takeMin == less) ? r[e] : q;
            }
        }
        for (; j >= 1; j >>= 1) {                   // in-thread: registers
            #pragma unroll
            for (int e = 0; e < VPT; ++e) {
                int p = e ^ j;
                if (p > e) {
                    int i = tid * VPT + e;
                    bool up = ((i & k) == 0);
                    u64 a = r[e], bkey = r[p];
                    if (up ? (a > bkey) : (a < bkey)) { r[e] = bkey; r[p] = a; }
                }
            }
        }
    }
    __syncthreads();
    #pragma unroll
    for (int e = 0; e < VPT; ++e) lds[tid * VPT + e] = r[e];
    __syncthreads();
}

// ---------------------------------------------------------------------------
// Kernel 1: decode -> corner boxes (B,N,4) + scores (B,C,N) class-major.
// ---------------------------------------------------------------------------
__global__ __launch_bounds__(256) void decode_kernel(
    const float* __restrict__ fm0, const float* __restrict__ fm1,
    const float* __restrict__ fm2, const float* __restrict__ anchors,
    float* __restrict__ boxes, float* __restrict__ scores)
{
    int t = blockIdx.x * 256 + threadIdx.x;
    if (t >= BATCH * NTOT) return;
    int b = t / NTOT, n = t % NTOT;
    const float* fm; int g, arow, local;
    if (n < N0)           { fm = fm0; g = 16; arow = 6; local = n; }
    else if (n < N0 + N1) { fm = fm1; g = 32; arow = 3; local = n - N0; }
    else                  { fm = fm2; g = 64; arow = 0; local = n - (N0 + N1); }
    int cell = local / 3, a = local % 3;
    int gy = cell / g, gx = cell % g;
    const float* p = fm + ((size_t)((b * g + gy) * g + gx) * 75 + (size_t)a * 25);
    float s = 512.0f / (float)g;   // power of two
    float cx = (sigm(p[0]) + (float)gx) * s;
    float cy = (sigm(p[1]) + (float)gy) * s;
    float w = exp_f32cr(p[2]) * anchors[(arow + a) * 2 + 0];
    float h = exp_f32cr(p[3]) * anchors[(arow + a) * 2 + 1];
    float conf = sigm(p[4]);
    float* bo = boxes + (size_t)t * 4;
    bo[0] = cx - w * 0.5f;
    bo[1] = cy - h * 0.5f;
    bo[2] = cx + w * 0.5f;
    bo[3] = cy + h * 0.5f;
    size_t sb = (size_t)b * NUM_CLASS * NTOT + (size_t)n;
    #pragma unroll
    for (int c = 0; c < NUM_CLASS; ++c)
        scores[sb + (size_t)c * NTOT] = conf * sigm(p[5 + c]);
}

// ---------------------------------------------------------------------------
// Kernel 2a: per-(batch,class) compact + register-bitonic sort -> global.
// key = (~score_bits << 32) | idx : ascending == (score desc, idx asc),
// identical to jnp.argsort(-s) stable order.
// ---------------------------------------------------------------------------
__global__ __launch_bounds__(NMS_W) void sort_kernel(
    const float* __restrict__ scores, u64* __restrict__ skeys,
    int* __restrict__ scnt_g)
{
    __shared__ u64 keys[SORT_N];          // 64 KB
    __shared__ unsigned scnt_s;

    const int tid = threadIdx.x;
    const int wlane = tid & 63;
    const int bc = blockIdx.x;            // b*NUM_CLASS + c

    if (tid == 0) scnt_s = 0u;
    __syncthreads();

    const float* sc = scores + (size_t)bc * NTOT;
    for (int n0 = 0; n0 < NTOT; n0 += NMS_W) {
        int n = n0 + tid;
        float s = (n < NTOT) ? sc[n] : -1.0f;
        bool pass = s > SCORE_THRESH;
        u64 m = __ballot(pass);
        unsigned base = 0;
        if (wlane == 0 && m) base = atomicAdd(&scnt_s, (unsigned)__popcll(m));
        base = __shfl(base, 0);
        if (pass) {
            unsigned pos = base + (unsigned)__popcll(m & ((1ull << wlane) - 1ull));
            if (pos < CAND_CAP) {
                unsigned sbits = ~__float_as_uint(s);
                keys[pos] = ((u64)sbits << 32) | (unsigned)n;
            }
        }
    }
    __syncthreads();
    int cnt = (int)scnt_s; if (cnt > CAND_CAP) cnt = CAND_CAP;
    for (int i = cnt + tid; i < SORT_N; i += NMS_W) keys[i] = ~0ull;
    __syncthreads();

    bitonic_reg_sort<SORT_N / NMS_W>(keys, tid, NMS_W);

    u64* ko = skeys + (size_t)bc * SORT_N;
    #pragma unroll
    for (int r = 0; r < SORT_N / NMS_W; ++r)
        ko[r * NMS_W + tid] = keys[r * NMS_W + tid];
    if (tid == 0) scnt_g[bc] = cnt;
}

// ---------------------------------------------------------------------------
// Kernel 2b: greedy scan, ONE WAVE per (b,c) problem — zero barriers in the
// resolve; pre-check pipelined 4-deep against sentinel-padded kept list.
// Greedy == ref's 150-iter suppress loop.
// ---------------------------------------------------------------------------
__global__ __launch_bounds__(64) void scan_kernel(
    const float* __restrict__ boxes, const u64* __restrict__ skeys,
    const int* __restrict__ scnt_g,
    int* __restrict__ kept_idx, float* __restrict__ kept_score)
{
    __shared__ float4 kept[MAX_BOXES + 4];   // sentinel-padded to group of 4
    const int lane = threadIdx.x;
    const int bc = blockIdx.x;
    const int b  = bc / NUM_CLASS;

    // sentinel (1e30,...): inter=0 exactly, ka=0 -> iou = 0/(carea) = 0 <= thr
    for (int i = lane; i < MAX_BOXES + 4; i += 64)
        kept[i] = make_float4(1e30f, 1e30f, 1e30f, 1e30f);
    __syncthreads();

    const u64* keys = skeys + (size_t)bc * SORT_N;
    int cnt = scnt_g[bc]; if (cnt > CAND_CAP) cnt = CAND_CAP;
    const float* bbase = boxes + (size_t)b * NTOT * 4;
    const size_t obase = (size_t)bc * MAX_BOXES;
    int nk = 0;

    for (int s0 = 0; s0 < cnt && nk < MAX_BOXES; s0 += 64) {
        int i = s0 + lane;
        int state = 1;                    // 0=survivor, 1=rejected, 2=kept
        float4 c4 = make_float4(0.f, 0.f, 0.f, 0.f);
        float cs = 0.0f, carea = 0.0f; int cn = -1;
        if (i < cnt) {
            u64 key = keys[i];
            cn = (int)(key & 0xffffffffull);
            cs = __uint_as_float(~(unsigned)(key >> 32));
            c4 = *(const float4*)(bbase + (size_t)cn * 4);
            carea = (c4.z - c4.x) * (c4.w - c4.y);
            state = 0;
            int nk4 = (nk + 3) & ~3;
            for (int kk = 0; kk < nk4; kk += 4) {   // 4 independent loads/trip
                float4 k0 = kept[kk], k1 = kept[kk + 1];
                float4 k2 = kept[kk + 2], k3 = kept[kk + 3];
                bool rej = iou_rej(k0, c4, carea) | iou_rej(k1, c4, carea)
                         | iou_rej(k2, c4, carea) | iou_rej(k3, c4, carea);
                if (rej) { state = 1; break; }
            }
        }
        // wave-serial resolve: ballot + shfl, no barriers
        while (nk < MAX_BOXES) {
            u64 m = __ballot(state == 0);
            if (!m) break;
            int fi = (int)__builtin_ctzll(m);
            float4 kb;
            kb.x = __shfl(c4.x, fi); kb.y = __shfl(c4.y, fi);
            kb.z = __shfl(c4.z, fi); kb.w = __shfl(c4.w, fi);
            int   kn = __shfl(cn, fi);
            float ks = __shfl(cs, fi);
            if (lane == 0) {
                kept[nk] = kb;
                kept_idx  [obase + nk] = kn;
                kept_score[obase + nk] = ks;
            }
            if (lane == fi) state = 2;
            else if (state == 0 && iou_rej(kb, c4, carea)) state = 1;
            ++nk;
        }
        __syncthreads();   // lane0's kept[] writes -> visible for next pre-check
    }
    for (int kx = nk + lane; kx < MAX_BOXES; kx += 64) {
        kept_idx  [obase + kx] = -1;
        kept_score[obase + kx] = -1.0f;
    }
}

// ---------------------------------------------------------------------------
// Kernel 3: per-image top-150 over 3000 kept entries (ties: lower flat pos).
// ---------------------------------------------------------------------------
__global__ __launch_bounds__(TOPK_W) void topk_kernel(
    const float* __restrict__ boxes, const int* __restrict__ kept_idx,
    const float* __restrict__ kept_score, float* __restrict__ out)
{
    __shared__ u64 keys[TOPK_N];
    const int tid = threadIdx.x;
    const int b = blockIdx.x;
    const int FLAT = NUM_CLASS * MAX_BOXES;   // 3000

    for (int f = tid; f < TOPK_N; f += TOPK_W) {
        u64 key = ~0ull;
        if (f < FLAT) {
            int idx = kept_idx[(size_t)b * FLAT + f];
            float s = (idx >= 0) ? kept_score[(size_t)b * FLAT + f] : -1.0f;
            unsigned u = __float_as_uint(s);
            unsigned mm = (u & 0x80000000u) ? ~u : (u | 0x80000000u);
            key = ((u64)(~mm) << 32) | (unsigned)f;  // ascending = score desc, pos asc
        }
        keys[f] = key;
    }
    __syncthreads();

    bitonic_reg_sort<TOPK_N / TOPK_W>(keys, tid, TOPK_W);

    if (tid < MAX_BOXES) {
        u64 key = keys[tid];
        int f = (int)(key & 0xffffffffull);
        float sc = -1.0f; int idx = -1;
        if (f < FLAT) {
            idx = kept_idx[(size_t)b * FLAT + f];
            if (idx >= 0) sc = kept_score[(size_t)b * FLAT + f];
        }
        bool ok = (idx >= 0) && (sc > 0.0f);
        float bx0 = -1.0f, bx1 = -1.0f, bx2 = -1.0f, bx3 = -1.0f;
        float lab = -1.0f;
        if (ok) {
            const float* bp = boxes + ((size_t)b * NTOT + idx) * 4;
            bx0 = bp[0]; bx1 = bp[1]; bx2 = bp[2]; bx3 = bp[3];
            lab = (float)(f / MAX_BOXES);
        } else {
            sc = -1.0f;
        }
        float* ob = out + ((size_t)b * MAX_BOXES + tid) * 4;
        ob[0] = bx0; ob[1] = bx1; ob[2] = bx2; ob[3] = bx3;
        out[(size_t)BATCH * MAX_BOXES * 4 + (size_t)b * MAX_BOXES + tid] = sc;
        out[(size_t)BATCH * MAX_BOXES * 5 + (size_t)b * MAX_BOXES + tid] = lab;
    }
}

extern "C" void kernel_launch(void* const* d_in, const int* in_sizes, int n_in,
                              void* d_out, int out_size, void* d_ws, size_t ws_size,
                              hipStream_t stream) {
    const float* fm0 = (const float*)d_in[0];
    const float* fm1 = (const float*)d_in[1];
    const float* fm2 = (const float*)d_in[2];
    const float* anchors = (const float*)d_in[3];
    float* out = (float*)d_out;

    // workspace carve (all 16B-aligned)
    float* boxes  = (float*)d_ws;                                   // B*N*4        (8.25 MB)
    float* scores = boxes + (size_t)BATCH * NTOT * 4;               // B*C*N        (41.3 MB)
    u64*   skeys  = (u64*)(scores + (size_t)BATCH * NUM_CLASS * NTOT); // B*C*SORT_N (40 MB)
    int*   scnt   = (int*)(skeys + (size_t)BATCH * NUM_CLASS * SORT_N);
    int*   kept_idx   = scnt + BATCH * NUM_CLASS;
    float* kept_score = (float*)(kept_idx + (size_t)BATCH * NUM_CLASS * MAX_BOXES);

    int total = BATCH * NTOT;
    decode_kernel<<<(total + 255) / 256, 256, 0, stream>>>(fm0, fm1, fm2, anchors, boxes, scores);
    sort_kernel<<<BATCH * NUM_CLASS, NMS_W, 0, stream>>>(scores, skeys, scnt);
    scan_kernel<<<BATCH * NUM_CLASS, 64, 0, stream>>>(boxes, skeys, scnt, kept_idx, kept_score);
    topk_kernel<<<BATCH, TOPK_W, 0, stream>>>(boxes, kept_idx, kept_score, out);
}

// Round 6
// 419.517 us; speedup vs baseline: 3.5965x; 1.0866x over previous
//
#include <hip/hip_runtime.h>

#define BATCH 32
#define NUM_CLASS 20
#define NTOT 16128      // 768 + 3072 + 12288
#define N0 768
#define N1 3072
#define MAX_BOXES 150
#define SORT_N 8192
#define CAND_CAP 7600
#define TOPK_N 4096     // >= NUM_CLASS*MAX_BOXES = 3000
#define SCORE_THRESH 0.3f
#define IOU_THRESH 0.1f
#define NMS_W 1024
#define TOPK_W 1024

typedef unsigned long long u64;

// exp via double, rounded once to f32 (correctly-rounded center, minimizes
// distance to numpy's f32 exp). Rest of sigmoid stays stepwise-f32.
__device__ __forceinline__ float exp_f32cr(float x) { return (float)exp((double)x); }
__device__ __forceinline__ float sigm(float x) { return 1.0f / (1.0f + exp_f32cr(-x)); }

// iou with precomputed keep-area (ka computed once at keep time -> identical
// f32 value as ref's inline (kb.z-kb.x)*(kb.w-kb.y); comparison bit-exact).
__device__ __forceinline__ bool iou_rej2(float4 kb, float ka, float4 c4, float carea) {
    float ix1 = fmaxf(kb.x, c4.x), iy1 = fmaxf(kb.y, c4.y);
    float ix2 = fminf(kb.z, c4.z), iy2 = fminf(kb.w, c4.w);
    float inter = fmaxf(ix2 - ix1, 0.0f) * fmaxf(iy2 - iy1, 0.0f);
    return (inter / (ka + carea - inter)) > IOU_THRESH;   // exact ref math
}

// Bank-conflict swizzle: inject bits 4-7 into bits 0-3 (bijective, upper->lower
// triangular XOR). Turns the 16-way conflict of contiguous-8 u64 ownership
// into ~4-way on cross-wave exchanges.
__device__ __forceinline__ int phys_idx(int i) { return i ^ ((i >> 4) & 0xF); }

// ---------------------------------------------------------------------------
// Register-blocked bitonic sort core over nthreads*VPT u64 keys.
// Thread t owns contiguous logical elements [t*VPT, (t+1)*VPT) in r[].
// LDS holds elements at phys_idx() positions; caller fills lds[phys_idx(i)]
// before calling. On return r[] is sorted (lds contents stale).
//   j <  VPT         : in-register compare-exchange
//   VPT <= j < 64*VPT: __shfl_xor lane exchange
//   j >= 64*VPT      : swizzled LDS exchange (2 barriers/stage)
// ---------------------------------------------------------------------------
template<int VPT>
__device__ __forceinline__ void bitonic_reg_core(u64 (&r)[VPT], u64* lds, int tid, int nthreads) {
    const int N = nthreads * VPT;
    #pragma unroll
    for (int e = 0; e < VPT; ++e) r[e] = lds[phys_idx(tid * VPT + e)];

    for (int k = 2; k <= N; k <<= 1) {
        int j = k >> 1;
        for (; j >= 64 * VPT; j >>= 1) {            // cross-wave: swizzled LDS
            __syncthreads();
            #pragma unroll
            for (int e = 0; e < VPT; ++e) lds[phys_idx(tid * VPT + e)] = r[e];
            __syncthreads();
            #pragma unroll
            for (int e = 0; e < VPT; ++e) {
                int i = tid * VPT + e;
                u64 q = lds[phys_idx(i ^ j)];
                bool takeMin = (((i & k) == 0) == ((i & j) == 0));
                bool less = r[e] < q;
                r[e] = (takeMin == less) ? r[e] : q;
            }
        }
        for (; j >= VPT; j >>= 1) {                 // in-wave: shfl_xor
            int ld = j / VPT;
            #pragma unroll
            for (int e = 0; e < VPT; ++e) {
                unsigned lo = (unsigned)r[e], hi = (unsigned)(r[e] >> 32);
                lo = (unsigned)__shfl_xor((int)lo, ld);
                hi = (unsigned)__shfl_xor((int)hi, ld);
                u64 q = ((u64)hi << 32) | lo;
                int i = tid * VPT + e;
                bool takeMin = (((i & k) == 0) == ((i & j) == 0));
                bool less = r[e] < q;
                r[e] = (takeMin == less) ? r[e] : q;
            }
        }
        for (; j >= 1; j >>= 1) {                   // in-thread: registers
            #pragma unroll
            for (int e = 0; e < VPT; ++e) {
                int p = e ^ j;
                if (p > e) {
                    int i = tid * VPT + e;
                    bool up = ((i & k) == 0);
                    u64 a = r[e], bkey = r[p];
                    if (up ? (a > bkey) : (a < bkey)) { r[e] = bkey; r[p] = a; }
                }
            }
        }
    }
}

// ---------------------------------------------------------------------------
// Kernel 1: decode -> corner boxes (B,N,4) + scores (B,C,N) class-major.
// ---------------------------------------------------------------------------
__global__ __launch_bounds__(256) void decode_kernel(
    const float* __restrict__ fm0, const float* __restrict__ fm1,
    const float* __restrict__ fm2, const float* __restrict__ anchors,
    float* __restrict__ boxes, float* __restrict__ scores)
{
    int t = blockIdx.x * 256 + threadIdx.x;
    if (t >= BATCH * NTOT) return;
    int b = t / NTOT, n = t % NTOT;
    const float* fm; int g, arow, local;
    if (n < N0)           { fm = fm0; g = 16; arow = 6; local = n; }
    else if (n < N0 + N1) { fm = fm1; g = 32; arow = 3; local = n - N0; }
    else                  { fm = fm2; g = 64; arow = 0; local = n - (N0 + N1); }
    int cell = local / 3, a = local % 3;
    int gy = cell / g, gx = cell % g;
    const float* p = fm + ((size_t)((b * g + gy) * g + gx) * 75 + (size_t)a * 25);
    float s = 512.0f / (float)g;   // power of two
    float cx = (sigm(p[0]) + (float)gx) * s;
    float cy = (sigm(p[1]) + (float)gy) * s;
    float w = exp_f32cr(p[2]) * anchors[(arow + a) * 2 + 0];
    float h = exp_f32cr(p[3]) * anchors[(arow + a) * 2 + 1];
    float conf = sigm(p[4]);
    float* bo = boxes + (size_t)t * 4;
    bo[0] = cx - w * 0.5f;
    bo[1] = cy - h * 0.5f;
    bo[2] = cx + w * 0.5f;
    bo[3] = cy + h * 0.5f;
    size_t sb = (size_t)b * NUM_CLASS * NTOT + (size_t)n;
    #pragma unroll
    for (int c = 0; c < NUM_CLASS; ++c)
        scores[sb + (size_t)c * NTOT] = conf * sigm(p[5 + c]);
}

// ---------------------------------------------------------------------------
// Kernel 2a: per-(batch,class) compact + register-bitonic sort -> global.
// key = (~score_bits << 32) | idx : ascending == (score desc, idx asc),
// identical to jnp.argsort(-s) stable order. Keys unique (idx) so
// compaction order doesn't matter. Sorted keys stored to global straight
// from registers (no LDS writeback).
// ---------------------------------------------------------------------------
__global__ __launch_bounds__(NMS_W) void sort_kernel(
    const float* __restrict__ scores, u64* __restrict__ skeys,
    int* __restrict__ scnt_g)
{
    __shared__ u64 keys[SORT_N];          // 64 KB
    __shared__ unsigned scnt_s;

    const int tid = threadIdx.x;
    const int wlane = tid & 63;
    const int bc = blockIdx.x;            // b*NUM_CLASS + c

    if (tid == 0) scnt_s = 0u;
    __syncthreads();

    const float* sc = scores + (size_t)bc * NTOT;
    for (int n0 = 0; n0 < NTOT; n0 += NMS_W) {
        int n = n0 + tid;
        float s = (n < NTOT) ? sc[n] : -1.0f;
        bool pass = s > SCORE_THRESH;
        u64 m = __ballot(pass);
        unsigned base = 0;
        if (wlane == 0 && m) base = atomicAdd(&scnt_s, (unsigned)__popcll(m));
        base = __shfl(base, 0);
        if (pass) {
            unsigned pos = base + (unsigned)__popcll(m & ((1ull << wlane) - 1ull));
            if (pos < CAND_CAP) {
                unsigned sbits = ~__float_as_uint(s);
                keys[phys_idx((int)pos)] = ((u64)sbits << 32) | (unsigned)n;
            }
        }
    }
    __syncthreads();
    int cnt = (int)scnt_s; if (cnt > CAND_CAP) cnt = CAND_CAP;
    for (int i = cnt + tid; i < SORT_N; i += NMS_W) keys[phys_idx(i)] = ~0ull;
    __syncthreads();

    u64 r[SORT_N / NMS_W];
    bitonic_reg_core<SORT_N / NMS_W>(r, keys, tid, NMS_W);

    // direct register->global store: thread t owns [8t, 8t+8) (64B, coalesced)
    u64* ko = skeys + (size_t)bc * SORT_N;
    #pragma unroll
    for (int e = 0; e < SORT_N / NMS_W; ++e)
        ko[tid * (SORT_N / NMS_W) + e] = r[e];
    if (tid == 0) scnt_g[bc] = cnt;
}

// ---------------------------------------------------------------------------
// Kernel 2b: greedy scan, ONE WAVE per (b,c) — zero barriers in resolve.
// Pre-check pipelined 8-deep vs sentinel-padded kept list with precomputed
// areas; next chunk's key+box prefetched under the pre-check.
// Greedy == ref's 150-iter suppress loop.
// ---------------------------------------------------------------------------
__global__ __launch_bounds__(64) void scan_kernel(
    const float* __restrict__ boxes, const u64* __restrict__ skeys,
    const int* __restrict__ scnt_g,
    int* __restrict__ kept_idx, float* __restrict__ kept_score)
{
    __shared__ float4 kept[MAX_BOXES + 8];   // sentinel-padded to group of 8
    __shared__ float  karea_s[MAX_BOXES + 8];
    const int lane = threadIdx.x;
    const int bc = blockIdx.x;
    const int b  = bc / NUM_CLASS;

    // sentinel (1e30)^4: inter=0, ka=0 -> iou = 0/carea = 0 <= thr (carea>0)
    for (int i = lane; i < MAX_BOXES + 8; i += 64) {
        kept[i] = make_float4(1e30f, 1e30f, 1e30f, 1e30f);
        karea_s[i] = 0.0f;
    }
    __syncthreads();

    const u64* keys = skeys + (size_t)bc * SORT_N;
    int cnt = scnt_g[bc]; if (cnt > CAND_CAP) cnt = CAND_CAP;
    const float* bbase = boxes + (size_t)b * NTOT * 4;
    const size_t obase = (size_t)bc * MAX_BOXES;
    int nk = 0;

    // software pipeline: key+box for chunk 0 loaded up front
    // (keys[] is SORT_N-long and ~0-padded, so unguarded key loads are safe:
    //  cnt<=7600 -> max index 7726 < 8192)
    u64 key_cur = keys[lane];
    int  cn_cur = (int)(key_cur & 0xffffffffull);
    bool lv_cur = (lane < cnt);
    float4 c4_cur = lv_cur ? *(const float4*)(bbase + (size_t)cn_cur * 4)
                           : make_float4(0.f, 0.f, 0.f, 0.f);

    for (int s0 = 0; s0 < cnt && nk < MAX_BOXES; s0 += 64) {
        // issue next chunk's loads before the long pre-check
        u64 key_nxt = keys[s0 + 64 + lane];
        int  cn_nxt = (int)(key_nxt & 0xffffffffull);
        bool lv_nxt = (s0 + 64 + lane) < cnt;
        float4 c4_nxt = lv_nxt ? *(const float4*)(bbase + (size_t)cn_nxt * 4)
                               : make_float4(0.f, 0.f, 0.f, 0.f);

        int state = 1;                    // 0=survivor, 1=rejected, 2=kept
        float cs = __uint_as_float(~(unsigned)(key_cur >> 32));
        float carea = (c4_cur.z - c4_cur.x) * (c4_cur.w - c4_cur.y);
        if (lv_cur) {
            state = 0;
            int nk8 = (nk + 7) & ~7;
            for (int kk = 0; kk < nk8; kk += 8) {   // 8 independent loads/trip
                bool rej = false;
                #pragma unroll
                for (int u = 0; u < 8; ++u)
                    rej |= iou_rej2(kept[kk + u], karea_s[kk + u], c4_cur, carea);
                if (rej) { state = 1; break; }
            }
        }
        // wave-serial resolve: ballot + shfl, no barriers
        while (nk < MAX_BOXES) {
            u64 m = __ballot(state == 0);
            if (!m) break;
            int fi = (int)__builtin_ctzll(m);
            float4 kb;
            kb.x = __shfl(c4_cur.x, fi); kb.y = __shfl(c4_cur.y, fi);
            kb.z = __shfl(c4_cur.z, fi); kb.w = __shfl(c4_cur.w, fi);
            int   kn = __shfl(cn_cur, fi);
            float ks = __shfl(cs, fi);
            float ka = __shfl(carea, fi);
            if (lane == 0) {
                kept[nk] = kb;
                karea_s[nk] = ka;
                kept_idx  [obase + nk] = kn;
                kept_score[obase + nk] = ks;
            }
            if (lane == fi) state = 2;
            else if (state == 0 && iou_rej2(kb, ka, c4_cur, carea)) state = 1;
            ++nk;
        }
        key_cur = key_nxt; cn_cur = cn_nxt; lv_cur = lv_nxt; c4_cur = c4_nxt;
        __syncthreads();   // lane0's kept[]/karea_s[] writes -> next pre-check
    }
    for (int kx = nk + lane; kx < MAX_BOXES; kx += 64) {
        kept_idx  [obase + kx] = -1;
        kept_score[obase + kx] = -1.0f;
    }
}

// ---------------------------------------------------------------------------
// Kernel 3: per-image top-150 over 3000 kept entries (ties: lower flat pos).
// ---------------------------------------------------------------------------
__global__ __launch_bounds__(TOPK_W) void topk_kernel(
    const float* __restrict__ boxes, const int* __restrict__ kept_idx,
    const float* __restrict__ kept_score, float* __restrict__ out)
{
    __shared__ u64 keys[TOPK_N];
    const int tid = threadIdx.x;
    const int b = blockIdx.x;
    const int FLAT = NUM_CLASS * MAX_BOXES;   // 3000

    for (int f = tid; f < TOPK_N; f += TOPK_W) {
        u64 key = ~0ull;
        if (f < FLAT) {
            int idx = kept_idx[(size_t)b * FLAT + f];
            float s = (idx >= 0) ? kept_score[(size_t)b * FLAT + f] : -1.0f;
            unsigned u = __float_as_uint(s);
            unsigned mm = (u & 0x80000000u) ? ~u : (u | 0x80000000u);
            key = ((u64)(~mm) << 32) | (unsigned)f;  // ascending = score desc, pos asc
        }
        keys[phys_idx(f)] = key;
    }
    __syncthreads();

    u64 r[TOPK_N / TOPK_W];
    bitonic_reg_core<TOPK_N / TOPK_W>(r, keys, tid, TOPK_W);

    // writeback (swizzled) so the first 150 can be read by index
    __syncthreads();
    #pragma unroll
    for (int e = 0; e < TOPK_N / TOPK_W; ++e)
        keys[phys_idx(tid * (TOPK_N / TOPK_W) + e)] = r[e];
    __syncthreads();

    if (tid < MAX_BOXES) {
        u64 key = keys[phys_idx(tid)];
        int f = (int)(key & 0xffffffffull);
        float sc = -1.0f; int idx = -1;
        if (f < FLAT) {
            idx = kept_idx[(size_t)b * FLAT + f];
            if (idx >= 0) sc = kept_score[(size_t)b * FLAT + f];
        }
        bool ok = (idx >= 0) && (sc > 0.0f);
        float bx0 = -1.0f, bx1 = -1.0f, bx2 = -1.0f, bx3 = -1.0f;
        float lab = -1.0f;
        if (ok) {
            const float* bp = boxes + ((size_t)b * NTOT + idx) * 4;
            bx0 = bp[0]; bx1 = bp[1]; bx2 = bp[2]; bx3 = bp[3];
            lab = (float)(f / MAX_BOXES);
        } else {
            sc = -1.0f;
        }
        float* ob = out + ((size_t)b * MAX_BOXES + tid) * 4;
        ob[0] = bx0; ob[1] = bx1; ob[2] = bx2; ob[3] = bx3;
        out[(size_t)BATCH * MAX_BOXES * 4 + (size_t)b * MAX_BOXES + tid] = sc;
        out[(size_t)BATCH * MAX_BOXES * 5 + (size_t)b * MAX_BOXES + tid] = lab;
    }
}

extern "C" void kernel_launch(void* const* d_in, const int* in_sizes, int n_in,
                              void* d_out, int out_size, void* d_ws, size_t ws_size,
                              hipStream_t stream) {
    const float* fm0 = (const float*)d_in[0];
    const float* fm1 = (const float*)d_in[1];
    const float* fm2 = (const float*)d_in[2];
    const float* anchors = (const float*)d_in[3];
    float* out = (float*)d_out;

    // workspace carve (all 16B-aligned)
    float* boxes  = (float*)d_ws;                                   // B*N*4        (8.25 MB)
    float* scores = boxes + (size_t)BATCH * NTOT * 4;               // B*C*N        (41.3 MB)
    u64*   skeys  = (u64*)(scores + (size_t)BATCH * NUM_CLASS * NTOT); // B*C*SORT_N (40 MB)
    int*   scnt   = (int*)(skeys + (size_t)BATCH * NUM_CLASS * SORT_N);
    int*   kept_idx   = scnt + BATCH * NUM_CLASS;
    float* kept_score = (float*)(kept_idx + (size_t)BATCH * NUM_CLASS * MAX_BOXES);

    int total = BATCH * NTOT;
    decode_kernel<<<(total + 255) / 256, 256, 0, stream>>>(fm0, fm1, fm2, anchors, boxes, scores);
    sort_kernel<<<BATCH * NUM_CLASS, NMS_W, 0, stream>>>(scores, skeys, scnt);
    scan_kernel<<<BATCH * NUM_CLASS, 64, 0, stream>>>(boxes, skeys, scnt, kept_idx, kept_score);
    topk_kernel<<<BATCH, TOPK_W, 0, stream>>>(boxes, kept_idx, kept_score, out);
}